// Round 5
// baseline (232.469 us; speedup 1.0000x reference)
//
#include <hip/hip_runtime.h>

#define NTOT 100000

typedef float f32x4 __attribute__((ext_vector_type(4)));
typedef short s16x8 __attribute__((ext_vector_type(8)));
typedef unsigned short u16;
typedef unsigned int u32;

__device__ __forceinline__ u16 bfbits(float f) {
    return __builtin_bit_cast(u16, (__bf16)f);
}
__device__ __forceinline__ u32 packbf2(float a, float b) {
    return (u32)bfbits(a) | ((u32)bfbits(b) << 16);
}
__device__ __forceinline__ float bf2f(u16 u) {
    u32 v = ((u32)u) << 16;
    return __builtin_bit_cast(float, v);
}
__device__ __forceinline__ s16x8 cvt8(const float* __restrict__ p) {
    f32x4 lo = *(const f32x4*)p;
    f32x4 hi = *(const f32x4*)(p + 4);
    s16x8 r;
#pragma unroll
    for (int e = 0; e < 4; ++e) r[e] = (short)bfbits(lo[e]);
#pragma unroll
    for (int e = 0; e < 4; ++e) r[4 + e] = (short)bfbits(hi[e]);
    return r;
}
// async global->LDS, 16B per lane; LDS dest = wave-uniform base + lane*16
__device__ __forceinline__ void gload16(const void* g, void* lds) {
    __builtin_amdgcn_global_load_lds(
        (const __attribute__((address_space(1))) u32*)g,
        (__attribute__((address_space(3))) u32*)lds, 16, 0, 0);
}

// ---------------- kernel 1: Cayley weights -------------------------------
__global__ void k_weights(const float* __restrict__ ev, const float* __restrict__ hp,
                          const float* __restrict__ ap, float* __restrict__ br,
                          float* __restrict__ bi) {
    int k = threadIdx.x;
    float h = hp[0], alpha = ap[0];
    float t = h * (ev[k] - alpha);
    float inv = 1.0f / (t * t + 1.0f);
    float b_re = (t * t - 1.0f) * inv;
    float b_im = -2.0f * t * inv;
    float cr = b_re, ci = b_im;
    br[k] = cr; bi[k] = ci;
#pragma unroll
    for (int j = 1; j < 8; ++j) {
        float nr = cr * b_re - ci * b_im;
        float ni = cr * b_im + ci * b_re;
        cr = nr; ci = ni;
        br[j * 256 + k] = cr;
        bi[j * 256 + k] = ci;
    }
}

// ---------------- kernel 2: P_partial(bf16) = E^T @ x --------------------
// grid = 256 chunks (1 block/CU); block 1024 (16 waves), full 256k x 256i.
// Partials land in d_out (scratch until gemm2 overwrites it).
__global__ __launch_bounds__(1024, 2) void k_gemm1(
    const float* __restrict__ E, const float* __restrict__ X,
    u16* __restrict__ Pp, int NB) {
    __shared__ alignas(16) u16 Et[2][256 * 64];   // 2 x 32 KB
    __shared__ alignas(16) u16 Xt[2][256 * 64];   // 2 x 32 KB

    int chunk = blockIdx.x;
    int nStart = chunk * NB;
    int nEnd = min(nStart + NB, NTOT);
    if (nEnd <= nStart) return;

    int t = threadIdx.x, lane = t & 63, w = t >> 6;
    int wk = w & 3, wi = w >> 2;          // 64k, 64i per wave
    int l15 = lane & 15, lhi = lane >> 4;
    int np = t & 31, cq = t >> 5;         // staging: n-pair 0..31, col-quad 0..31

    f32x4 v[8];
    f32x4 acc[4][4] = {};
    int nwin = (nEnd - nStart + 63) >> 6;

#define G1_LOAD(WIN)                                                         \
    {                                                                        \
        int nb_ = nStart + (WIN) * 64 + np * 2;                              \
        int na_ = (nb_ < nEnd) ? nb_ : nStart;                               \
        int nb2_ = (nb_ + 1 < nEnd) ? (nb_ + 1) : nStart;                    \
        float ma_ = (nb_ < nEnd) ? 1.0f : 0.0f;                              \
        float mb_ = (nb_ + 1 < nEnd) ? 1.0f : 0.0f;                          \
        _Pragma("unroll") for (int p = 0; p < 2; ++p) {                      \
            int c4 = (p * 32 + cq) * 4;                                      \
            v[p * 4 + 0] = *(const f32x4*)(E + (size_t)na_ * 256 + c4) * ma_; \
            v[p * 4 + 1] = *(const f32x4*)(E + (size_t)nb2_ * 256 + c4) * mb_;\
            v[p * 4 + 2] = *(const f32x4*)(X + (size_t)na_ * 256 + c4) * ma_; \
            v[p * 4 + 3] = *(const f32x4*)(X + (size_t)nb2_ * 256 + c4) * mb_;\
        }                                                                    \
    }

#define G1_WRITE(BUF)                                                        \
    _Pragma("unroll") for (int p = 0; p < 2; ++p) {                          \
        _Pragma("unroll") for (int e = 0; e < 4; ++e) {                      \
            int c = (p * 32 + cq) * 4 + e;                                   \
            int byte = c * 128 + (((np >> 2) ^ (c & 7)) * 16) + (np & 3) * 4; \
            *(u32*)((char*)Et[BUF] + byte) = packbf2(v[p * 4 + 0][e], v[p * 4 + 1][e]); \
            *(u32*)((char*)Xt[BUF] + byte) = packbf2(v[p * 4 + 2][e], v[p * 4 + 3][e]); \
        }                                                                    \
    }

#define G1_COMPUTE(BUF)                                                      \
    _Pragma("unroll") for (int ns = 0; ns < 2; ++ns) {                       \
        s16x8 a[4], b[4];                                                    \
        _Pragma("unroll") for (int m = 0; m < 4; ++m) {                      \
            int row = wk * 64 + m * 16 + l15;                                \
            int slot = (ns * 4 + lhi) ^ (row & 7);                           \
            a[m] = *(const s16x8*)((char*)Et[BUF] + row * 128 + slot * 16);  \
        }                                                                    \
        _Pragma("unroll") for (int c = 0; c < 4; ++c) {                      \
            int row = wi * 64 + c * 16 + l15;                                \
            int slot = (ns * 4 + lhi) ^ (row & 7);                           \
            b[c] = *(const s16x8*)((char*)Xt[BUF] + row * 128 + slot * 16);  \
        }                                                                    \
        _Pragma("unroll") for (int m = 0; m < 4; ++m)                        \
            _Pragma("unroll") for (int c = 0; c < 4; ++c)                    \
                acc[m][c] = __builtin_amdgcn_mfma_f32_16x16x32_bf16(         \
                    a[m], b[c], acc[m][c], 0, 0, 0);                         \
    }

    G1_LOAD(0);
    for (int win = 0; win < nwin; ++win) {
        asm volatile("s_waitcnt lgkmcnt(0)" ::: "memory");
        __builtin_amdgcn_s_barrier();
        G1_WRITE(win & 1);
        if (win + 1 < nwin) G1_LOAD(win + 1);
        asm volatile("s_waitcnt lgkmcnt(0)" ::: "memory");
        __builtin_amdgcn_s_barrier();
        G1_COMPUTE(win & 1);
    }
#undef G1_LOAD
#undef G1_WRITE
#undef G1_COMPUTE

    u16* dst = Pp + (size_t)chunk * 65536;
#pragma unroll
    for (int m = 0; m < 4; ++m) {
#pragma unroll
        for (int cf = 0; cf < 4; ++cf) {
            int ii = wi * 64 + cf * 16 + l15;
#pragma unroll
            for (int r = 0; r < 4; ++r) {
                int kk = wk * 64 + m * 16 + lhi * 4 + r;
                dst[kk * 256 + ii] = bfbits(acc[m][cf][r]);
            }
        }
    }
}

// ---------------- kernel 3: reduce bf16 partials -> Pb (bf16) ------------
// 128 blocks x 256 thr; thread owns one u32 (2 bf16); coalesced per chunk.
__global__ void k_reduceP(const u32* __restrict__ Pp32,
                          u32* __restrict__ Pb32, int chunks) {
    int idx = blockIdx.x * 256 + threadIdx.x;   // 0..32767
    float s0 = 0.f, s1 = 0.f;
    for (int c = 0; c < chunks; ++c) {
        u32 vv = Pp32[(size_t)c * 32768 + idx];
        s0 += bf2f((u16)(vv & 0xffff));
        s1 += bf2f((u16)(vv >> 16));
    }
    Pb32[idx] = packbf2(s0, s1);
}

// ---------------- kernel 4: T[c] = P @ W_c^T (17 small GEMMs) ------------
__global__ __launch_bounds__(256, 4) void k_smallgemm(
    const u16* __restrict__ Pb, const float* __restrict__ c0,
    const float* __restrict__ cjr, const float* __restrict__ cji,
    float* __restrict__ T) {
    int c = blockIdx.x >> 3;
    int k0 = (blockIdx.x & 7) * 32;
    const float* W = (c == 0) ? c0 : (c <= 8 ? (cjr + (size_t)(c - 1) * 65536)
                                             : (cji + (size_t)(c - 9) * 65536));
    int t = threadIdx.x, lane = t & 63, wi = t >> 6;
    int l15 = lane & 15, lhi = lane >> 4;
    f32x4 acc[2][4] = {};
    for (int is = 0; is < 256; is += 32) {
        s16x8 a[2], b[4];
#pragma unroll
        for (int m = 0; m < 2; ++m)
            a[m] = *(const s16x8*)(Pb + (k0 + m * 16 + l15) * 256 + is + lhi * 8);
#pragma unroll
        for (int cf = 0; cf < 4; ++cf)
            b[cf] = cvt8(W + (size_t)(wi * 64 + cf * 16 + l15) * 256 + is + lhi * 8);
#pragma unroll
        for (int m = 0; m < 2; ++m)
#pragma unroll
            for (int cf = 0; cf < 4; ++cf)
                acc[m][cf] = __builtin_amdgcn_mfma_f32_16x16x32_bf16(
                    a[m], b[cf], acc[m][cf], 0, 0, 0);
    }
    float* dst = T + (size_t)c * 65536;
#pragma unroll
    for (int m = 0; m < 2; ++m) {
#pragma unroll
        for (int cf = 0; cf < 4; ++cf) {
            int oo = wi * 64 + cf * 16 + l15;
#pragma unroll
            for (int r = 0; r < 4; ++r) {
                int kk = k0 + m * 16 + lhi * 4 + r;
                dst[kk * 256 + oo] = acc[m][cf][r];
            }
        }
    }
}

// ---------------- kernel 5: combine T -> Qt bf16 (transposed) ------------
__global__ void k_combine(const float* __restrict__ T, const float* __restrict__ br,
                          const float* __restrict__ bi, u16* __restrict__ Qt) {
    int t = threadIdx.x;
    int k = blockIdx.x * 4 + (t >> 6);
    int o4 = (t & 63) * 4;
    f32x4 q = *(const f32x4*)(T + (size_t)k * 256 + o4);
#pragma unroll
    for (int j = 0; j < 8; ++j) {
        float brv = br[j * 256 + k], biv = bi[j * 256 + k];
        f32x4 tr = *(const f32x4*)(T + (size_t)(1 + j) * 65536 + k * 256 + o4);
        f32x4 ti = *(const f32x4*)(T + (size_t)(9 + j) * 65536 + k * 256 + o4);
        q += 2.0f * (brv * tr - biv * ti);
    }
#pragma unroll
    for (int e = 0; e < 4; ++e) Qt[(size_t)(o4 + e) * 256 + k] = bfbits(q[e]);
}

// ---------------- kernel 6: out = E @ Q ----------------------------------
// grid 1024 = 4 o-groups x 256 n-chunks; block 256 (4 waves).
// Block tile: 32n x 64o; Qt slab 32 KB staged once (gload_lds, pre-swz);
// E tiles reg-staged -> bf16 LDS (16 KB dbuf x2). Wave = 16n x 32o:
// per KSTEP 3 ds_read_b128 -> 2 MFMA. 3125 tiles exact, no masking.
__global__ __launch_bounds__(256, 2) void k_gemm2(
    const float* __restrict__ E, const u16* __restrict__ Qt,
    float* __restrict__ out) {
    __shared__ alignas(16) u16 QtL[64 * 256];       // 32 KB
    __shared__ alignas(16) u16 Ebuf[2][32 * 256];   // 2 x 16 KB

    int b = blockIdx.x;
    int og = b & 3;
    int nc = b >> 2;
    int tile0 = nc * 12 + min(nc, 53);       // 3125 = 256*12 + 53
    int nt = (nc < 53) ? 13 : 12;

    int t = threadIdx.x, lane = t & 63, w = t >> 6;
    int l15 = lane & 15, lhi = lane >> 4;
    int wn = w & 1, wo = w >> 1;

    // ---- stage Qt slab rows og*64..+63 (pre-swizzled source) ----
#pragma unroll
    for (int r = 0; r < 8; ++r) {
        int L = r * 256 + t;                 // 0..2047
        int o = L >> 5, s = L & 31;
        gload16(Qt + (size_t)(og * 64 + o) * 256 + ((s ^ (o & 7)) * 8),
                (char*)QtL + (size_t)(r * 256 + w * 64) * 16);
    }

    f32x4 rv[8];

#define G2_LOADE(TI)                                                         \
    {                                                                        \
        int nb0 = (tile0 + (TI)) * 32;                                       \
        _Pragma("unroll") for (int j = 0; j < 8; ++j)                        \
            rv[j] = *(const f32x4*)(E + (size_t)(nb0 + j * 4 + w) * 256 + lane * 4); \
    }

#define G2_WRITEE(BUF)                                                       \
    {                                                                        \
        _Pragma("unroll") for (int j = 0; j < 8; ++j) {                      \
            int r = j * 4 + w;                                               \
            int slot = (lane >> 1) ^ (r & 7);                                \
            u32* p = (u32*)((char*)Ebuf[BUF] + r * 512 + slot * 16 +         \
                            (lane & 1) * 8);                                 \
            p[0] = packbf2(rv[j][0], rv[j][1]);                              \
            p[1] = packbf2(rv[j][2], rv[j][3]);                              \
        }                                                                    \
    }

#define G2_COMPUTE(BUF)                                                      \
    {                                                                        \
        _Pragma("unroll") for (int ks = 0; ks < 8; ++ks) {                   \
            int nrow = wn * 16 + l15;                                        \
            s16x8 ef = *(const s16x8*)((char*)Ebuf[BUF] + nrow * 512 +       \
                        (((ks * 4 + lhi) ^ (nrow & 7)) * 16));               \
            _Pragma("unroll") for (int m = 0; m < 2; ++m) {                  \
                int orow = wo * 32 + m * 16 + l15;                           \
                s16x8 af = *(const s16x8*)((char*)QtL + orow * 512 +         \
                            (((ks * 4 + lhi) ^ (orow & 7)) * 16));           \
                acc[m] = __builtin_amdgcn_mfma_f32_16x16x32_bf16(            \
                    af, ef, acc[m], 0, 0, 0);                                \
            }                                                                \
        }                                                                    \
    }

    G2_LOADE(0);
    asm volatile("s_waitcnt vmcnt(0)" ::: "memory");  // QtL in LDS, rv landed
    G2_WRITEE(0);
    __syncthreads();

    for (int i = 0; i < nt; ++i) {
        f32x4 acc[2] = {};
        if (i + 1 < nt) G2_LOADE(i + 1);       // issue early (T14)
        G2_COMPUTE(i & 1);                     // loads fly under MFMA
        if (i + 1 < nt) G2_WRITEE((i + 1) & 1);
        int n = (tile0 + i) * 32 + wn * 16 + l15;
#pragma unroll
        for (int m = 0; m < 2; ++m)
            *(f32x4*)(out + (size_t)n * 256 + og * 64 + wo * 32 + m * 16 + lhi * 4)
                = acc[m];
        __syncthreads();
    }
#undef G2_LOADE
#undef G2_WRITEE
#undef G2_COMPUTE
}

// ---------------- host ---------------------------------------------------
extern "C" void kernel_launch(void* const* d_in, const int* in_sizes, int n_in,
                              void* d_out, int out_size, void* d_ws, size_t ws_size,
                              hipStream_t stream) {
    const float* x   = (const float*)d_in[0];
    const float* ev  = (const float*)d_in[1];
    const float* E   = (const float*)d_in[2];
    const float* hp  = (const float*)d_in[3];
    const float* ap  = (const float*)d_in[4];
    const float* c0  = (const float*)d_in[5];
    const float* cjr = (const float*)d_in[6];
    const float* cji = (const float*)d_in[7];
    float* out = (float*)d_out;

    char* ws = (char*)d_ws;
    float* br = (float*)(ws + 0);                 // 8 KB
    float* bi = (float*)(ws + 8192);              // 8 KB
    u16*   Pb = (u16*)(ws + 16384);               // 128 KB
    u16*   Qt = (u16*)(ws + 147456);              // 128 KB
    float* T  = (float*)(ws + 278528);            // 17*256 KB -> end 4.73 MB

    // P partials: bf16, 256 chunks x 128 KB = 33.5 MB -- scratch inside
    // d_out (102.4 MB). reduceP consumes them before gemm2 overwrites all
    // of d_out. Performance no longer depends on ws_size.
    u16* Pp = (u16*)d_out;
    const int chunks = 256;
    const int NB = (NTOT + chunks - 1) / chunks;  // 391

    k_weights<<<1, 256, 0, stream>>>(ev, hp, ap, br, bi);
    k_gemm1<<<chunks, 1024, 0, stream>>>(E, x, Pp, NB);
    k_reduceP<<<128, 256, 0, stream>>>((const u32*)Pp, (u32*)Pb, chunks);
    k_smallgemm<<<17 * 8, 256, 0, stream>>>(Pb, c0, cjr, cji, T);
    k_combine<<<64, 256, 0, stream>>>(T, br, bi, Qt);
    k_gemm2<<<1024, 256, 0, stream>>>(E, Qt, out);
}

// Round 7
// 207.821 us; speedup vs baseline: 1.1186x; 1.1186x over previous
//
#include <hip/hip_runtime.h>

#define NTOT 100000

typedef float f32x4 __attribute__((ext_vector_type(4)));
typedef short s16x8 __attribute__((ext_vector_type(8)));
typedef short s16x4 __attribute__((ext_vector_type(4)));
typedef unsigned int u32x2 __attribute__((ext_vector_type(2)));
typedef unsigned short u16;
typedef unsigned int u32;

__device__ __forceinline__ u16 bfbits(float f) {
    return __builtin_bit_cast(u16, (__bf16)f);
}
__device__ __forceinline__ u32 packbf2(float a, float b) {
    return (u32)bfbits(a) | ((u32)bfbits(b) << 16);
}
__device__ __forceinline__ float bf2f(u16 u) {
    u32 v = ((u32)u) << 16;
    return __builtin_bit_cast(float, v);
}
__device__ __forceinline__ s16x8 cvt8(const float* __restrict__ p) {
    f32x4 lo = *(const f32x4*)p;
    f32x4 hi = *(const f32x4*)(p + 4);
    s16x8 r;
#pragma unroll
    for (int e = 0; e < 4; ++e) r[e] = (short)bfbits(lo[e]);
#pragma unroll
    for (int e = 0; e < 4; ++e) r[4 + e] = (short)bfbits(hi[e]);
    return r;
}

// ds_read_b64_tr_b16 semantics (m156+m162 reconciled): per-lane addr; each
// 16-lane group's 8B fetches concatenate (lane order) into a 128B logical
// [4][16]-bf16 tile; lane k receives elements {k, k+16, k+32, k+48}.
// => supplying addr = subtile_base + (l&15)*8 yields lane k, elem j =
//    subtile[row j][col k]  (the transpose).
__device__ __forceinline__ s16x4 trread(unsigned a) {
    s16x4 d;
    asm volatile("ds_read_b64_tr_b16 %0, %1" : "=v"(d) : "v"(a));
    return d;
}
__device__ __forceinline__ s16x4 trread2k(unsigned a) {
    s16x4 d;
    asm volatile("ds_read_b64_tr_b16 %0, %1 offset:2048" : "=v"(d) : "v"(a));
    return d;
}
struct S2 { s16x4 lo, hi; };
__device__ __forceinline__ s16x8 cat44(s16x4 lo, s16x4 hi) {
    S2 s{lo, hi};
    return __builtin_bit_cast(s16x8, s);
}
// rule 18: lgkmcnt(0) + sched_barrier after inline-asm ds reads
#define LGKM0_FENCE()                                         \
    do {                                                      \
        asm volatile("s_waitcnt lgkmcnt(0)" ::: "memory");    \
        __builtin_amdgcn_sched_barrier(0);                    \
    } while (0)

// ---------------- kernel 1: Cayley weights -------------------------------
__global__ void k_weights(const float* __restrict__ ev, const float* __restrict__ hp,
                          const float* __restrict__ ap, float* __restrict__ br,
                          float* __restrict__ bi) {
    int k = threadIdx.x;
    float h = hp[0], alpha = ap[0];
    float t = h * (ev[k] - alpha);
    float inv = 1.0f / (t * t + 1.0f);
    float b_re = (t * t - 1.0f) * inv;
    float b_im = -2.0f * t * inv;
    float cr = b_re, ci = b_im;
    br[k] = cr; bi[k] = ci;
#pragma unroll
    for (int j = 1; j < 8; ++j) {
        float nr = cr * b_re - ci * b_im;
        float ni = cr * b_im + ci * b_re;
        cr = nr; ci = ni;
        br[j * 256 + k] = cr;
        bi[j * 256 + k] = ci;
    }
}

// ---------------- kernel 2: P_partial(bf16) = E^T @ x --------------------
// grid = 256 chunks; block 1024 (16 waves), full 256k x 256i output.
// Window = 32 n-rows. Global loads coalesced (256B segments). LDS layout:
// [n/4][c/16] subtiles of [4 n][16 c] bf16 (128 B). MFMA fragments via
// ds_read_b64_tr_b16 with per-lane addr = subtile_base + l15*8.
__global__ __launch_bounds__(1024, 4) void k_gemm1(
    const float* __restrict__ E, const float* __restrict__ X,
    u16* __restrict__ Pp, int NB) {
    __shared__ alignas(16) u16 Et[8192];   // 16 KB: 32n x 256c subtiled
    __shared__ alignas(16) u16 Xt[8192];   // 16 KB

    int chunk = blockIdx.x;
    int nStart = chunk * NB;
    int nEnd = min(nStart + NB, NTOT);
    if (nEnd <= nStart) return;

    int t = threadIdx.x, lane = t & 63, w = t >> 6;
    int wk = w & 3, wi = w >> 2;           // compute roles: 64k x 64i / wave
    int l15 = lane & 15, lhi = lane >> 4;
    int rg = w >> 1, qh = w & 1;           // staging roles: row-group, q-half

    unsigned EtB = (unsigned)(size_t)&Et[0];
    unsigned XtB = (unsigned)(size_t)&Xt[0];

    // staging constants: 2 quarters q0,q1; rotated row-offsets d, col-chunks g
    int q0 = qh * 2, q1 = q0 + 1;
    int d0 = ((lane & 3) + q0) & 3, d1 = ((lane & 3) + q1) & 3;
    int g0 = q0 * 16 + (lane >> 2), g1 = q1 * 16 + (lane >> 2);
    unsigned wb0 = (unsigned)((rg * 16 + (g0 >> 2)) * 128 + d0 * 32 + (g0 & 3) * 8);
    unsigned wb1 = (unsigned)((rg * 16 + (g1 >> 2)) * 128 + d1 * 32 + (g1 & 3) * 8);
    // tr-read bases: subtile (ng = lhi*2, cg) at (ng*16+cg)*128, + l15*8
    unsigned aB = EtB + (unsigned)(lhi * 4096 + wk * 512 + l15 * 8);
    unsigned bB = XtB + (unsigned)(lhi * 4096 + wi * 512 + l15 * 8);

    f32x4 vE0, vE1, vX0, vX1;
    f32x4 acc[4][4] = {};
    int nwin = (nEnd - nStart + 31) >> 5;

#define G1_LOAD(WIN)                                                        \
    {                                                                       \
        int n0_ = nStart + (WIN) * 32 + rg * 4;                             \
        int r0_ = n0_ + d0, r1_ = n0_ + d1;                                 \
        int a0_ = (r0_ < nEnd) ? r0_ : nStart;                              \
        int a1_ = (r1_ < nEnd) ? r1_ : nStart;                              \
        float m0_ = (r0_ < nEnd) ? 1.f : 0.f;                               \
        float m1_ = (r1_ < nEnd) ? 1.f : 0.f;                               \
        vE0 = *(const f32x4*)(E + (size_t)a0_ * 256 + g0 * 4) * m0_;        \
        vE1 = *(const f32x4*)(E + (size_t)a1_ * 256 + g1 * 4) * m1_;        \
        vX0 = *(const f32x4*)(X + (size_t)a0_ * 256 + g0 * 4) * m0_;        \
        vX1 = *(const f32x4*)(X + (size_t)a1_ * 256 + g1 * 4) * m1_;        \
    }

#define G1_WRITE()                                                          \
    {                                                                       \
        *(u32x2*)((char*)Et + wb0) =                                        \
            (u32x2){packbf2(vE0[0], vE0[1]), packbf2(vE0[2], vE0[3])};      \
        *(u32x2*)((char*)Et + wb1) =                                        \
            (u32x2){packbf2(vE1[0], vE1[1]), packbf2(vE1[2], vE1[3])};      \
        *(u32x2*)((char*)Xt + wb0) =                                        \
            (u32x2){packbf2(vX0[0], vX0[1]), packbf2(vX0[2], vX0[3])};      \
        *(u32x2*)((char*)Xt + wb1) =                                        \
            (u32x2){packbf2(vX1[0], vX1[1]), packbf2(vX1[2], vX1[3])};      \
    }

#define G1_COMPUTE()                                                        \
    {                                                                       \
        s16x4 ta0[4], ta1[4], tb0[4], tb1[4];                               \
        _Pragma("unroll") for (int m = 0; m < 4; ++m) {                     \
            ta0[m] = trread(aB + m * 128);                                  \
            ta1[m] = trread2k(aB + m * 128);                                \
        }                                                                   \
        _Pragma("unroll") for (int c = 0; c < 4; ++c) {                     \
            tb0[c] = trread(bB + c * 128);                                  \
            tb1[c] = trread2k(bB + c * 128);                                \
        }                                                                   \
        LGKM0_FENCE();                                                      \
        s16x8 a[4], b[4];                                                   \
        _Pragma("unroll") for (int m = 0; m < 4; ++m) a[m] = cat44(ta0[m], ta1[m]); \
        _Pragma("unroll") for (int c = 0; c < 4; ++c) b[c] = cat44(tb0[c], tb1[c]); \
        _Pragma("unroll") for (int m = 0; m < 4; ++m)                       \
            _Pragma("unroll") for (int c = 0; c < 4; ++c)                   \
                acc[m][c] = __builtin_amdgcn_mfma_f32_16x16x32_bf16(        \
                    a[m], b[c], acc[m][c], 0, 0, 0);                        \
    }

    G1_LOAD(0);
    for (int win = 0; win < nwin; ++win) {
        asm volatile("s_waitcnt lgkmcnt(0)" ::: "memory");
        __builtin_amdgcn_s_barrier();
        G1_WRITE();                         // compiler waits vmcnt for v*
        if (win + 1 < nwin) G1_LOAD(win + 1);
        asm volatile("s_waitcnt lgkmcnt(0)" ::: "memory");
        __builtin_amdgcn_s_barrier();
        G1_COMPUTE();                       // next loads fly underneath
    }
#undef G1_LOAD
#undef G1_WRITE
#undef G1_COMPUTE

    u16* dst = Pp + (size_t)chunk * 65536;
#pragma unroll
    for (int m = 0; m < 4; ++m) {
#pragma unroll
        for (int cf = 0; cf < 4; ++cf) {
            int ii = wi * 64 + cf * 16 + l15;
#pragma unroll
            for (int r = 0; r < 4; ++r) {
                int kk = wk * 64 + m * 16 + lhi * 4 + r;
                dst[kk * 256 + ii] = bfbits(acc[m][cf][r]);
            }
        }
    }
}

// ---------------- kernel 3: reduce bf16 partials -> Pb (bf16) ------------
__global__ void k_reduceP(const u32* __restrict__ Pp32,
                          u32* __restrict__ Pb32, int chunks) {
    int idx = blockIdx.x * 256 + threadIdx.x;   // 0..32767
    float s0 = 0.f, s1 = 0.f;
    for (int c = 0; c < chunks; ++c) {
        u32 vv = Pp32[(size_t)c * 32768 + idx];
        s0 += bf2f((u16)(vv & 0xffff));
        s1 += bf2f((u16)(vv >> 16));
    }
    Pb32[idx] = packbf2(s0, s1);
}

// ---------------- kernel 4: T[c] = P @ W_c^T (17 small GEMMs) ------------
__global__ __launch_bounds__(256, 4) void k_smallgemm(
    const u16* __restrict__ Pb, const float* __restrict__ c0,
    const float* __restrict__ cjr, const float* __restrict__ cji,
    float* __restrict__ T) {
    int c = blockIdx.x >> 3;
    int k0 = (blockIdx.x & 7) * 32;
    const float* W = (c == 0) ? c0 : (c <= 8 ? (cjr + (size_t)(c - 1) * 65536)
                                             : (cji + (size_t)(c - 9) * 65536));
    int t = threadIdx.x, lane = t & 63, wi = t >> 6;
    int l15 = lane & 15, lhi = lane >> 4;
    f32x4 acc[2][4] = {};
    for (int is = 0; is < 256; is += 32) {
        s16x8 a[2], b[4];
#pragma unroll
        for (int m = 0; m < 2; ++m)
            a[m] = *(const s16x8*)(Pb + (k0 + m * 16 + l15) * 256 + is + lhi * 8);
#pragma unroll
        for (int cf = 0; cf < 4; ++cf)
            b[cf] = cvt8(W + (size_t)(wi * 64 + cf * 16 + l15) * 256 + is + lhi * 8);
#pragma unroll
        for (int m = 0; m < 2; ++m)
#pragma unroll
            for (int cf = 0; cf < 4; ++cf)
                acc[m][cf] = __builtin_amdgcn_mfma_f32_16x16x32_bf16(
                    a[m], b[cf], acc[m][cf], 0, 0, 0);
    }
    float* dst = T + (size_t)c * 65536;
#pragma unroll
    for (int m = 0; m < 2; ++m) {
#pragma unroll
        for (int cf = 0; cf < 4; ++cf) {
            int oo = wi * 64 + cf * 16 + l15;
#pragma unroll
            for (int r = 0; r < 4; ++r) {
                int kk = k0 + m * 16 + lhi * 4 + r;
                dst[kk * 256 + oo] = acc[m][cf][r];
            }
        }
    }
}

// ---------------- kernel 5: combine T -> Qt bf16 (transposed) ------------
__global__ void k_combine(const float* __restrict__ T, const float* __restrict__ br,
                          const float* __restrict__ bi, u16* __restrict__ Qt) {
    int t = threadIdx.x;
    int k = blockIdx.x * 4 + (t >> 6);
    int o4 = (t & 63) * 4;
    f32x4 q = *(const f32x4*)(T + (size_t)k * 256 + o4);
#pragma unroll
    for (int j = 0; j < 8; ++j) {
        float brv = br[j * 256 + k], biv = bi[j * 256 + k];
        f32x4 tr = *(const f32x4*)(T + (size_t)(1 + j) * 65536 + k * 256 + o4);
        f32x4 ti = *(const f32x4*)(T + (size_t)(9 + j) * 65536 + k * 256 + o4);
        q += 2.0f * (brv * tr - biv * ti);
    }
#pragma unroll
    for (int e = 0; e < 4; ++e) Qt[(size_t)(o4 + e) * 256 + k] = bfbits(q[e]);
}

// ---------------- kernel 6: out = E @ Q ----------------------------------
// grid = 512 (2 o-halves x 256 n-slabs); block 512 (8 waves: 2 wn x 4 wo).
// Q-fragments af[2][8] held in REGISTERS (loaded once per block), reused
// over ~12 n-tiles. E staged reg->bf16 LDS (16 KB dbuf), XOR swizzle.
// One raw barrier per tile; out stores never drained (no vmcnt(0)).
__global__ __launch_bounds__(512, 4) void k_gemm2(
    const float* __restrict__ E, const u16* __restrict__ Qt,
    float* __restrict__ out) {
    __shared__ alignas(16) u16 Ebuf[2][32 * 256];   // 2 x 16 KB

    int b = blockIdx.x;
    int og = b & 1;
    int slab = b >> 1;                   // 0..255
    int tile0 = slab * 12 + min(slab, 53);   // 3125 = 256*12 + 53
    int nt = (slab < 53) ? 13 : 12;

    int t = threadIdx.x, lane = t & 63, w = t >> 6;
    int l15 = lane & 15, lhi = lane >> 4;
    int wn = w & 1, wo = w >> 1;         // wo 0..3
    int obase = og * 128 + wo * 32;
    int nrow = wn * 16 + l15;

    // Q fragments in registers: o = obase + m*16 + l15, k-slice ks
    s16x8 af[2][8];
#pragma unroll
    for (int m = 0; m < 2; ++m)
#pragma unroll
        for (int ks = 0; ks < 8; ++ks)
            af[m][ks] = *(const s16x8*)(Qt + (size_t)(obase + m * 16 + l15) * 256 +
                                        ks * 32 + lhi * 8);

    f32x4 rv[4];

#define G2_LOADE(TI)                                                        \
    {                                                                       \
        int nb0_ = (tile0 + (TI)) * 32 + w * 4;                             \
        _Pragma("unroll") for (int j = 0; j < 4; ++j)                       \
            rv[j] = *(const f32x4*)(E + (size_t)(nb0_ + j) * 256 + lane * 4); \
    }

#define G2_WRITEE(BUF)                                                      \
    _Pragma("unroll") for (int j = 0; j < 4; ++j) {                         \
        int r_ = w * 4 + j;                                                 \
        *(u32x2*)((char*)Ebuf[BUF] + r_ * 512 +                             \
                  (((lane >> 1) ^ (r_ & 7)) * 16) + (lane & 1) * 8) =       \
            (u32x2){packbf2(rv[j][0], rv[j][1]), packbf2(rv[j][2], rv[j][3])}; \
    }

    G2_LOADE(0);
    G2_WRITEE(0);                         // compiler inserts vmcnt for rv
    asm volatile("s_waitcnt lgkmcnt(0)" ::: "memory");
    __builtin_amdgcn_s_barrier();

    for (int i = 0; i < nt; ++i) {
        if (i + 1 < nt) G2_LOADE(i + 1);  // issue early (T14)
        f32x4 acc[2] = {};
        const char* Eb = (const char*)Ebuf[i & 1];
#pragma unroll
        for (int ks = 0; ks < 8; ++ks) {
            s16x8 ef = *(const s16x8*)(Eb + nrow * 512 +
                                       (((ks * 4 + lhi) ^ (nrow & 7)) * 16));
#pragma unroll
            for (int m = 0; m < 2; ++m)
                acc[m] = __builtin_amdgcn_mfma_f32_16x16x32_bf16(
                    af[m][ks], ef, acc[m], 0, 0, 0);
        }
        int n = (tile0 + i) * 32 + wn * 16 + l15;
#pragma unroll
        for (int m = 0; m < 2; ++m)
            *(f32x4*)(out + (size_t)n * 256 + obase + m * 16 + lhi * 4) = acc[m];
        if (i + 1 < nt) G2_WRITEE((i + 1) & 1);
        asm volatile("s_waitcnt lgkmcnt(0)" ::: "memory");
        __builtin_amdgcn_s_barrier();
    }
#undef G2_LOADE
#undef G2_WRITEE
}

// ---------------- host ---------------------------------------------------
extern "C" void kernel_launch(void* const* d_in, const int* in_sizes, int n_in,
                              void* d_out, int out_size, void* d_ws, size_t ws_size,
                              hipStream_t stream) {
    const float* x   = (const float*)d_in[0];
    const float* ev  = (const float*)d_in[1];
    const float* E   = (const float*)d_in[2];
    const float* hp  = (const float*)d_in[3];
    const float* ap  = (const float*)d_in[4];
    const float* c0  = (const float*)d_in[5];
    const float* cjr = (const float*)d_in[6];
    const float* cji = (const float*)d_in[7];
    float* out = (float*)d_out;

    char* ws = (char*)d_ws;
    float* br = (float*)(ws + 0);                 // 8 KB
    float* bi = (float*)(ws + 8192);              // 8 KB
    u16*   Pb = (u16*)(ws + 16384);               // 128 KB
    u16*   Qt = (u16*)(ws + 147456);              // 128 KB
    float* T  = (float*)(ws + 278528);            // 17*256 KB -> 4.73 MB

    // P partials (bf16, 256 x 128 KB = 33.5 MB) live in d_out scratch;
    // consumed by reduceP before gemm2 overwrites d_out (stream-ordered).
    u16* Pp = (u16*)d_out;
    const int chunks = 256;
    const int NB = (NTOT + chunks - 1) / chunks;  // 392

    k_weights<<<1, 256, 0, stream>>>(ev, hp, ap, br, bi);
    k_gemm1<<<chunks, 1024, 0, stream>>>(E, x, Pp, NB);
    k_reduceP<<<128, 256, 0, stream>>>((const u32*)Pp, (u32*)Pb, chunks);
    k_smallgemm<<<17 * 8, 256, 0, stream>>>(Pb, c0, cjr, cji, T);
    k_combine<<<64, 256, 0, stream>>>(T, br, bi, Qt);
    k_gemm2<<<512, 512, 0, stream>>>(E, Qt, out);
}

// Round 8
// 188.021 us; speedup vs baseline: 1.2364x; 1.1053x over previous
//
#include <hip/hip_runtime.h>

#define NTOT 100000

typedef float f32x4 __attribute__((ext_vector_type(4)));
typedef short s16x8 __attribute__((ext_vector_type(8)));
typedef short s16x4 __attribute__((ext_vector_type(4)));
typedef unsigned int u32x2 __attribute__((ext_vector_type(2)));
typedef unsigned short u16;
typedef unsigned int u32;

__device__ __forceinline__ u16 bfbits(float f) {
    return __builtin_bit_cast(u16, (__bf16)f);
}
__device__ __forceinline__ u32 packbf2(float a, float b) {
    return (u32)bfbits(a) | ((u32)bfbits(b) << 16);
}
__device__ __forceinline__ float bf2f(u16 u) {
    u32 v = ((u32)u) << 16;
    return __builtin_bit_cast(float, v);
}
__device__ __forceinline__ s16x8 cvt8(const float* __restrict__ p) {
    f32x4 lo = *(const f32x4*)p;
    f32x4 hi = *(const f32x4*)(p + 4);
    s16x8 r;
#pragma unroll
    for (int e = 0; e < 4; ++e) r[e] = (short)bfbits(lo[e]);
#pragma unroll
    for (int e = 0; e < 4; ++e) r[4 + e] = (short)bfbits(hi[e]);
    return r;
}

// ds_read_b64_tr_b16 (HW-verified r7): per-lane addr = subtile_base + l15*8
// yields lane k, elem j = subtile[row j][col k] of a [4][16]-bf16 tile.
__device__ __forceinline__ s16x4 trread(unsigned a) {
    s16x4 d;
    asm volatile("ds_read_b64_tr_b16 %0, %1" : "=v"(d) : "v"(a));
    return d;
}
__device__ __forceinline__ s16x4 trread2k(unsigned a) {
    s16x4 d;
    asm volatile("ds_read_b64_tr_b16 %0, %1 offset:2048" : "=v"(d) : "v"(a));
    return d;
}
struct S2 { s16x4 lo, hi; };
__device__ __forceinline__ s16x8 cat44(s16x4 lo, s16x4 hi) {
    S2 s{lo, hi};
    return __builtin_bit_cast(s16x8, s);
}
// rule 18: lgkmcnt(0) + sched_barrier after inline-asm ds reads
#define LGKM0_FENCE()                                         \
    do {                                                      \
        asm volatile("s_waitcnt lgkmcnt(0)" ::: "memory");    \
        __builtin_amdgcn_sched_barrier(0);                    \
    } while (0)

// ---------------- kernel 1: Cayley weights -------------------------------
__global__ void k_weights(const float* __restrict__ ev, const float* __restrict__ hp,
                          const float* __restrict__ ap, float* __restrict__ br,
                          float* __restrict__ bi) {
    int k = threadIdx.x;
    float h = hp[0], alpha = ap[0];
    float t = h * (ev[k] - alpha);
    float inv = 1.0f / (t * t + 1.0f);
    float b_re = (t * t - 1.0f) * inv;
    float b_im = -2.0f * t * inv;
    float cr = b_re, ci = b_im;
    br[k] = cr; bi[k] = ci;
#pragma unroll
    for (int j = 1; j < 8; ++j) {
        float nr = cr * b_re - ci * b_im;
        float ni = cr * b_im + ci * b_re;
        cr = nr; ci = ni;
        br[j * 256 + k] = cr;
        bi[j * 256 + k] = ci;
    }
}

// ---------------- kernel 2: P_partial(bf16) = E^T @ x --------------------
// grid = 256 chunks; block 1024 (16 waves), full 256k x 256i output.
// Window = 32 n-rows, DOUBLE-BUFFERED LDS (2 x 16 KB per operand); ONE
// barrier per window: COMPUTE(cur) -> WRITE(cur^1) -> LOAD(win+2) -> bar.
__global__ __launch_bounds__(1024, 4) void k_gemm1(
    const float* __restrict__ E, const float* __restrict__ X,
    u16* __restrict__ Pp, int NB) {
    __shared__ alignas(16) u16 Et[2][8192];   // 2 x 16 KB subtiled
    __shared__ alignas(16) u16 Xt[2][8192];   // 2 x 16 KB

    int chunk = blockIdx.x;
    int nStart = chunk * NB;
    int nEnd = min(nStart + NB, NTOT);
    if (nEnd <= nStart) return;

    int t = threadIdx.x, lane = t & 63, w = t >> 6;
    int wk = w & 3, wi = w >> 2;           // compute roles: 64k x 64i / wave
    int l15 = lane & 15, lhi = lane >> 4;
    int rg = w >> 1, qh = w & 1;           // staging roles: row-group, q-half

    unsigned EtB = (unsigned)(size_t)&Et[0][0];
    unsigned XtB = (unsigned)(size_t)&Xt[0][0];

    // staging constants: 2 quarters q0,q1; rotated row-offsets d, col-chunks g
    int q0 = qh * 2, q1 = q0 + 1;
    int d0 = ((lane & 3) + q0) & 3, d1 = ((lane & 3) + q1) & 3;
    int g0 = q0 * 16 + (lane >> 2), g1 = q1 * 16 + (lane >> 2);
    unsigned wb0 = (unsigned)((rg * 16 + (g0 >> 2)) * 128 + d0 * 32 + (g0 & 3) * 8);
    unsigned wb1 = (unsigned)((rg * 16 + (g1 >> 2)) * 128 + d1 * 32 + (g1 & 3) * 8);
    // tr-read bases: subtile (ng = lhi*2, cg) at (ng*16+cg)*128, + l15*8
    unsigned aB = EtB + (unsigned)(lhi * 4096 + wk * 512 + l15 * 8);
    unsigned bB = XtB + (unsigned)(lhi * 4096 + wi * 512 + l15 * 8);

    f32x4 vE0, vE1, vX0, vX1;
    f32x4 acc[4][4] = {};
    int nwin = (nEnd - nStart + 31) >> 5;

#define G1_LOAD(WIN)                                                        \
    {                                                                       \
        int n0_ = nStart + (WIN) * 32 + rg * 4;                             \
        int r0_ = n0_ + d0, r1_ = n0_ + d1;                                 \
        int a0_ = (r0_ < nEnd) ? r0_ : nStart;                              \
        int a1_ = (r1_ < nEnd) ? r1_ : nStart;                              \
        float m0_ = (r0_ < nEnd) ? 1.f : 0.f;                               \
        float m1_ = (r1_ < nEnd) ? 1.f : 0.f;                               \
        vE0 = *(const f32x4*)(E + (size_t)a0_ * 256 + g0 * 4) * m0_;        \
        vE1 = *(const f32x4*)(E + (size_t)a1_ * 256 + g1 * 4) * m1_;        \
        vX0 = *(const f32x4*)(X + (size_t)a0_ * 256 + g0 * 4) * m0_;        \
        vX1 = *(const f32x4*)(X + (size_t)a1_ * 256 + g1 * 4) * m1_;        \
    }

#define G1_WRITE(BUF)                                                       \
    {                                                                       \
        unsigned bo_ = (unsigned)(BUF) * 16384u;                            \
        *(u32x2*)((char*)Et + bo_ + wb0) =                                  \
            (u32x2){packbf2(vE0[0], vE0[1]), packbf2(vE0[2], vE0[3])};      \
        *(u32x2*)((char*)Et + bo_ + wb1) =                                  \
            (u32x2){packbf2(vE1[0], vE1[1]), packbf2(vE1[2], vE1[3])};      \
        *(u32x2*)((char*)Xt + bo_ + wb0) =                                  \
            (u32x2){packbf2(vX0[0], vX0[1]), packbf2(vX0[2], vX0[3])};      \
        *(u32x2*)((char*)Xt + bo_ + wb1) =                                  \
            (u32x2){packbf2(vX1[0], vX1[1]), packbf2(vX1[2], vX1[3])};      \
    }

#define G1_COMPUTE(BUF)                                                     \
    {                                                                       \
        unsigned bo_ = (unsigned)(BUF) * 16384u;                            \
        unsigned aB_ = aB + bo_, bB_ = bB + bo_;                            \
        s16x4 ta0[4], ta1[4], tb0[4], tb1[4];                               \
        _Pragma("unroll") for (int m = 0; m < 4; ++m) {                     \
            ta0[m] = trread(aB_ + m * 128);                                 \
            ta1[m] = trread2k(aB_ + m * 128);                               \
        }                                                                   \
        _Pragma("unroll") for (int c = 0; c < 4; ++c) {                     \
            tb0[c] = trread(bB_ + c * 128);                                 \
            tb1[c] = trread2k(bB_ + c * 128);                               \
        }                                                                   \
        LGKM0_FENCE();                                                      \
        s16x8 a[4], b[4];                                                   \
        _Pragma("unroll") for (int m = 0; m < 4; ++m) a[m] = cat44(ta0[m], ta1[m]); \
        _Pragma("unroll") for (int c = 0; c < 4; ++c) b[c] = cat44(tb0[c], tb1[c]); \
        _Pragma("unroll") for (int m = 0; m < 4; ++m)                       \
            _Pragma("unroll") for (int c = 0; c < 4; ++c)                   \
                acc[m][c] = __builtin_amdgcn_mfma_f32_16x16x32_bf16(        \
                    a[m], b[c], acc[m][c], 0, 0, 0);                        \
    }

    G1_LOAD(0);
    G1_WRITE(0);                            // prologue vmcnt stall (once)
    G1_LOAD(1);
    asm volatile("s_waitcnt lgkmcnt(0)" ::: "memory");
    __builtin_amdgcn_s_barrier();
    for (int win = 0; win < nwin; ++win) {
        int cur = win & 1;
        G1_COMPUTE(cur);
        if (win + 1 < nwin) G1_WRITE(cur ^ 1);   // loads(win+1): covered
        if (win + 2 < nwin) G1_LOAD(win + 2);    // 2 windows ahead
        asm volatile("s_waitcnt lgkmcnt(0)" ::: "memory");
        __builtin_amdgcn_s_barrier();
    }
#undef G1_LOAD
#undef G1_WRITE
#undef G1_COMPUTE

    u16* dst = Pp + (size_t)chunk * 65536;
#pragma unroll
    for (int m = 0; m < 4; ++m) {
#pragma unroll
        for (int cf = 0; cf < 4; ++cf) {
            int ii = wi * 64 + cf * 16 + l15;
#pragma unroll
            for (int r = 0; r < 4; ++r) {
                int kk = wk * 64 + m * 16 + lhi * 4 + r;
                dst[kk * 256 + ii] = bfbits(acc[m][cf][r]);
            }
        }
    }
}

// ---------------- kernel 3: reduce bf16 partials -> Pb (bf16) ------------
__global__ void k_reduceP(const u32* __restrict__ Pp32,
                          u32* __restrict__ Pb32, int chunks) {
    int idx = blockIdx.x * 256 + threadIdx.x;   // 0..32767
    float s0 = 0.f, s1 = 0.f;
    for (int c = 0; c < chunks; ++c) {
        u32 vv = Pp32[(size_t)c * 32768 + idx];
        s0 += bf2f((u16)(vv & 0xffff));
        s1 += bf2f((u16)(vv >> 16));
    }
    Pb32[idx] = packbf2(s0, s1);
}

// ---------------- kernel 4: T[c] = P @ W_c^T (17 small GEMMs) ------------
__global__ __launch_bounds__(256, 4) void k_smallgemm(
    const u16* __restrict__ Pb, const float* __restrict__ c0,
    const float* __restrict__ cjr, const float* __restrict__ cji,
    float* __restrict__ T) {
    int c = blockIdx.x >> 3;
    int k0 = (blockIdx.x & 7) * 32;
    const float* W = (c == 0) ? c0 : (c <= 8 ? (cjr + (size_t)(c - 1) * 65536)
                                             : (cji + (size_t)(c - 9) * 65536));
    int t = threadIdx.x, lane = t & 63, wi = t >> 6;
    int l15 = lane & 15, lhi = lane >> 4;
    f32x4 acc[2][4] = {};
    for (int is = 0; is < 256; is += 32) {
        s16x8 a[2], b[4];
#pragma unroll
        for (int m = 0; m < 2; ++m)
            a[m] = *(const s16x8*)(Pb + (k0 + m * 16 + l15) * 256 + is + lhi * 8);
#pragma unroll
        for (int cf = 0; cf < 4; ++cf)
            b[cf] = cvt8(W + (size_t)(wi * 64 + cf * 16 + l15) * 256 + is + lhi * 8);
#pragma unroll
        for (int m = 0; m < 2; ++m)
#pragma unroll
            for (int cf = 0; cf < 4; ++cf)
                acc[m][cf] = __builtin_amdgcn_mfma_f32_16x16x32_bf16(
                    a[m], b[cf], acc[m][cf], 0, 0, 0);
    }
    float* dst = T + (size_t)c * 65536;
#pragma unroll
    for (int m = 0; m < 2; ++m) {
#pragma unroll
        for (int cf = 0; cf < 4; ++cf) {
            int oo = wi * 64 + cf * 16 + l15;
#pragma unroll
            for (int r = 0; r < 4; ++r) {
                int kk = k0 + m * 16 + lhi * 4 + r;
                dst[kk * 256 + oo] = acc[m][cf][r];
            }
        }
    }
}

// ---------------- kernel 5: combine T -> Qt bf16 (transposed) ------------
__global__ void k_combine(const float* __restrict__ T, const float* __restrict__ br,
                          const float* __restrict__ bi, u16* __restrict__ Qt) {
    int t = threadIdx.x;
    int k = blockIdx.x * 4 + (t >> 6);
    int o4 = (t & 63) * 4;
    f32x4 q = *(const f32x4*)(T + (size_t)k * 256 + o4);
#pragma unroll
    for (int j = 0; j < 8; ++j) {
        float brv = br[j * 256 + k], biv = bi[j * 256 + k];
        f32x4 tr = *(const f32x4*)(T + (size_t)(1 + j) * 65536 + k * 256 + o4);
        f32x4 ti = *(const f32x4*)(T + (size_t)(9 + j) * 65536 + k * 256 + o4);
        q += 2.0f * (brv * tr - biv * ti);
    }
#pragma unroll
    for (int e = 0; e < 4; ++e) Qt[(size_t)(o4 + e) * 256 + k] = bfbits(q[e]);
}

// ---------------- kernel 6: out = E @ Q ----------------------------------
// grid = 512 (XCD-swizzled; 2 o-halves x 256 n-slabs); block 512 (8 waves).
// Q-fragments in REGISTERS; E staged via DEPTH-2 named reg sets (rvA/rvB)
// -> bf16 LDS dbuf; order: COMPUTE -> WRITEE(next) -> LOADE(i+2) -> bar.
__global__ __launch_bounds__(512, 4) void k_gemm2(
    const float* __restrict__ E, const u16* __restrict__ Qt,
    float* __restrict__ out) {
    __shared__ alignas(16) u16 Ebuf[2][32 * 256];   // 2 x 16 KB

    int b0 = blockIdx.x;
    int b = (b0 & 7) * 64 + (b0 >> 3);   // bijective XCD swizzle (512 = 8*64)
    int og = b & 1;
    int slab = b >> 1;                   // 0..255
    int tile0 = slab * 12 + min(slab, 53);   // 3125 = 256*12 + 53
    int nt = (slab < 53) ? 13 : 12;

    int t = threadIdx.x, lane = t & 63, w = t >> 6;
    int l15 = lane & 15, lhi = lane >> 4;
    int wn = w & 1, wo = w >> 1;         // wo 0..3
    int obase = og * 128 + wo * 32;
    int nrow = wn * 16 + l15;

    // Q fragments in registers: o = obase + m*16 + l15, k-slice ks
    s16x8 af[2][8];
#pragma unroll
    for (int m = 0; m < 2; ++m)
#pragma unroll
        for (int ks = 0; ks < 8; ++ks)
            af[m][ks] = *(const s16x8*)(Qt + (size_t)(obase + m * 16 + l15) * 256 +
                                        ks * 32 + lhi * 8);

    f32x4 rvA[4], rvB[4];

#define G2_LOADE(TI, RV)                                                    \
    {                                                                       \
        int nb0_ = (tile0 + (TI)) * 32 + w * 4;                             \
        _Pragma("unroll") for (int j = 0; j < 4; ++j)                       \
            RV[j] = *(const f32x4*)(E + (size_t)(nb0_ + j) * 256 + lane * 4); \
    }

#define G2_WRITEE(RV, BUF)                                                  \
    _Pragma("unroll") for (int j = 0; j < 4; ++j) {                         \
        int r_ = w * 4 + j;                                                 \
        *(u32x2*)((char*)Ebuf[BUF] + r_ * 512 +                             \
                  (((lane >> 1) ^ (r_ & 7)) * 16) + (lane & 1) * 8) =       \
            (u32x2){packbf2(RV[j][0], RV[j][1]), packbf2(RV[j][2], RV[j][3])}; \
    }

#define G2_TILE(I, BUF, WRV, LRV)                                           \
    {                                                                       \
        f32x4 acc[2] = {};                                                  \
        const char* Eb_ = (const char*)Ebuf[BUF];                           \
        _Pragma("unroll") for (int ks = 0; ks < 8; ++ks) {                  \
            s16x8 ef = *(const s16x8*)(Eb_ + nrow * 512 +                   \
                        (((ks * 4 + lhi) ^ (nrow & 7)) * 16));              \
            _Pragma("unroll") for (int m = 0; m < 2; ++m)                   \
                acc[m] = __builtin_amdgcn_mfma_f32_16x16x32_bf16(           \
                    af[m][ks], ef, acc[m], 0, 0, 0);                        \
        }                                                                   \
        int n_ = (tile0 + (I)) * 32 + wn * 16 + l15;                        \
        _Pragma("unroll") for (int m = 0; m < 2; ++m)                       \
            *(f32x4*)(out + (size_t)n_ * 256 + obase + m * 16 + lhi * 4) =  \
                acc[m];                                                     \
        if ((I) + 1 < nt) G2_WRITEE(WRV, (BUF) ^ 1);                        \
        if ((I) + 2 < nt) G2_LOADE((I) + 2, LRV);                           \
        asm volatile("s_waitcnt lgkmcnt(0)" ::: "memory");                  \
        __builtin_amdgcn_s_barrier();                                       \
    }

    G2_LOADE(0, rvA);
    G2_WRITEE(rvA, 0);                    // prologue vmcnt stall (once)
    G2_LOADE(1, rvB);
    asm volatile("s_waitcnt lgkmcnt(0)" ::: "memory");
    __builtin_amdgcn_s_barrier();

    for (int i = 0; i < nt; i += 2) {
        G2_TILE(i, 0, rvB, rvA);          // even tile: buf0; write rvB->buf1
        if (i + 1 < nt)
            G2_TILE(i + 1, 1, rvA, rvB);  // odd tile: buf1; write rvA->buf0
    }
#undef G2_LOADE
#undef G2_WRITEE
#undef G2_TILE
}

// ---------------- host ---------------------------------------------------
extern "C" void kernel_launch(void* const* d_in, const int* in_sizes, int n_in,
                              void* d_out, int out_size, void* d_ws, size_t ws_size,
                              hipStream_t stream) {
    const float* x   = (const float*)d_in[0];
    const float* ev  = (const float*)d_in[1];
    const float* E   = (const float*)d_in[2];
    const float* hp  = (const float*)d_in[3];
    const float* ap  = (const float*)d_in[4];
    const float* c0  = (const float*)d_in[5];
    const float* cjr = (const float*)d_in[6];
    const float* cji = (const float*)d_in[7];
    float* out = (float*)d_out;

    char* ws = (char*)d_ws;
    float* br = (float*)(ws + 0);                 // 8 KB
    float* bi = (float*)(ws + 8192);              // 8 KB
    u16*   Pb = (u16*)(ws + 16384);               // 128 KB
    u16*   Qt = (u16*)(ws + 147456);              // 128 KB
    float* T  = (float*)(ws + 278528);            // 17*256 KB -> 4.73 MB

    // P partials (bf16, 256 x 128 KB = 33.5 MB) live in d_out scratch;
    // consumed by reduceP before gemm2 overwrites d_out (stream-ordered).
    u16* Pp = (u16*)d_out;
    const int chunks = 256;
    const int NB = (NTOT + chunks - 1) / chunks;  // 392

    k_weights<<<1, 256, 0, stream>>>(ev, hp, ap, br, bi);
    k_gemm1<<<chunks, 1024, 0, stream>>>(E, x, Pp, NB);
    k_reduceP<<<128, 256, 0, stream>>>((const u32*)Pp, (u32*)Pb, chunks);
    k_smallgemm<<<17 * 8, 256, 0, stream>>>(Pb, c0, cjr, cji, T);
    k_combine<<<64, 256, 0, stream>>>(T, br, bi, Qt);
    k_gemm2<<<512, 512, 0, stream>>>(E, Qt, out);
}